// Round 2
// baseline (4664.055 us; speedup 1.0000x reference)
//
#include <hip/hip_runtime.h>
#include <hip/hip_bf16.h>

#define B_ 2
#define T_ 32768
#define CH_ 128
#define EC_ 512
#define ATOM_ 2048
#define FBK_ 512

typedef __attribute__((ext_vector_type(8))) short s16x8;
typedef __attribute__((ext_vector_type(4))) float f32x4;

__device__ __forceinline__ float bf2f(unsigned short u) {
    unsigned int v = ((unsigned int)u) << 16;
    union { unsigned int i; float f; } w; w.i = v; return w.f;
}
__device__ __forceinline__ unsigned short f2bf(float f) {
    union { float f; unsigned int i; } w; w.f = f;
    unsigned int lsb = (w.i >> 16) & 1u;
    w.i += 0x7fffu + lsb;
    return (unsigned short)(w.i >> 16);
}

// ---------------- filter bank: x[b,1,T] -> spec[b,128,T] ----------------
__global__ void k_fb(const float* __restrict__ x, const float* __restrict__ fbw,
                     float* __restrict__ spec) {
    __shared__ float xs[1024 + FBK_ + 4];
    int t0 = blockIdx.x * 1024;
    int bg = blockIdx.y;
    int b  = blockIdx.z;
    int tid = threadIdx.x;
    for (int i = tid; i < 1024 + FBK_ + 4; i += 256) {
        int gx = t0 - FBK_/2 + i;
        xs[i] = (gx >= 0 && gx < T_) ? x[(size_t)b*T_ + gx] : 0.f;
    }
    __syncthreads();
    int base = tid * 4;
    for (int bi = 0; bi < 16; ++bi) {
        int band = bg*16 + bi;
        const float* w = fbw + (size_t)band * FBK_;
        float a0=0.f,a1=0.f,a2=0.f,a3=0.f;
        float4 cur = *(const float4*)&xs[base];
        for (int k4 = 0; k4 < FBK_; k4 += 4) {
            float4 nxt = *(const float4*)&xs[base + k4 + 4];
            float w0 = w[k4], w1 = w[k4+1], w2 = w[k4+2], w3 = w[k4+3];
            a0 = fmaf(w0,cur.x,fmaf(w1,cur.y,fmaf(w2,cur.z,fmaf(w3,cur.w,a0))));
            a1 = fmaf(w0,cur.y,fmaf(w1,cur.z,fmaf(w2,cur.w,fmaf(w3,nxt.x,a1))));
            a2 = fmaf(w0,cur.z,fmaf(w1,cur.w,fmaf(w2,nxt.x,fmaf(w3,nxt.y,a2))));
            a3 = fmaf(w0,cur.w,fmaf(w1,nxt.x,fmaf(w2,nxt.y,fmaf(w3,nxt.z,a3))));
            cur = nxt;
        }
        size_t o = ((size_t)(b*CH_ + band))*T_ + t0 + base;
        float4 r; r.x=a0; r.y=a1; r.z=a2; r.w=a3;
        *(float4*)&spec[o] = r;
    }
}

// ---------------- generic 128->128 channel conv (K taps, dilation) ----------------
template<int KT, bool NORM, bool LRELU>
__global__ void k_conv(const float* __restrict__ in, const float* __restrict__ w,
                       const float* __restrict__ bias, const float* __restrict__ aff,
                       float* __restrict__ out, int dil) {
    int tid = threadIdx.x;
    int tl = tid & 63;
    int grp = __builtin_amdgcn_readfirstlane(tid >> 6);
    int b = blockIdx.y;
    int t = blockIdx.x * 64 + tl;
    int co_base = grp * 32;
    float acc[32];
#pragma unroll
    for (int i = 0; i < 32; ++i) acc[i] = 0.f;
    for (int ci = 0; ci < CH_; ++ci) {
        const float* ip = in + ((size_t)(b*CH_ + ci))*T_;
        float A_ = 1.f, Bb_ = 0.f;
        if (NORM) { A_ = aff[2*ci]; Bb_ = aff[2*ci+1]; }
        float xn[KT];
#pragma unroll
        for (int k = 0; k < KT; ++k) {
            int ti = t + (k - KT/2)*dil;
            int tc = min(max(ti, 0), T_-1);
            float v = ip[tc];
            float xv = NORM ? fmaf(v, A_, Bb_) : v;
            xn[k] = (ti == tc) ? xv : 0.f;    // zero-pad AFTER the BN fold
        }
#pragma unroll
        for (int cl = 0; cl < 32; ++cl) {
            const float* wp = w + ((size_t)(co_base + cl)*CH_ + ci)*KT;
            float s = 0.f;
#pragma unroll
            for (int k = 0; k < KT; ++k) s = fmaf(wp[k], xn[k], s);
            acc[cl] += s;
        }
    }
#pragma unroll
    for (int cl = 0; cl < 32; ++cl) {
        int co = co_base + cl;
        float v = acc[cl] + bias[co];
        if (LRELU) v = v >= 0.f ? v : 0.2f*v;
        out[((size_t)(b*CH_ + co))*T_ + t] = v;
    }
}

// ---------------- pointwise conv + residual + lrelu ----------------
__global__ void k_pw(const float* __restrict__ y1, const float* __restrict__ w,
                     const float* __restrict__ bias, const float* __restrict__ aff,
                     const float* __restrict__ a_prev, float* __restrict__ out) {
    __shared__ float lw[CH_*CH_];
    int tid = threadIdx.x;
    for (int i = tid; i < CH_*CH_; i += 256) lw[i] = w[i];
    __syncthreads();
    int tl = tid & 63;
    int grp = __builtin_amdgcn_readfirstlane(tid >> 6);
    int b = blockIdx.y;
    int t = blockIdx.x * 64 + tl;
    int co_base = grp * 32;
    float acc[32];
#pragma unroll
    for (int i = 0; i < 32; ++i) acc[i] = 0.f;
    for (int ci = 0; ci < CH_; ++ci) {
        float v = y1[((size_t)(b*CH_ + ci))*T_ + t];
#pragma unroll
        for (int cl = 0; cl < 32; ++cl)
            acc[cl] = fmaf(lw[(co_base+cl)*CH_ + ci], v, acc[cl]);
    }
#pragma unroll
    for (int cl = 0; cl < 32; ++cl) {
        int co = co_base + cl;
        float orig = a_prev[((size_t)(b*CH_ + co))*T_ + t];
        float on = fmaf(orig, aff[2*co], aff[2*co+1]);
        float vv = acc[cl] + bias[co] + on;
        vv = vv >= 0.f ? vv : 0.2f*vv;
        out[((size_t)(b*CH_ + co))*T_ + t] = vv;
    }
}

// ---------------- BN stats -> per-channel affine (A, B) ----------------
__global__ void k_stats(const float* __restrict__ a, const float* __restrict__ g,
                        const float* __restrict__ bb, float* __restrict__ aff) {
    int ch = blockIdx.x;
    int tid = threadIdx.x;
    float s = 0.f, s2 = 0.f;
    for (int idx = tid; idx < B_*T_; idx += 256) {
        int b = idx >> 15;
        int t = idx & (T_-1);
        float v = a[((size_t)(b*CH_ + ch))*T_ + t];
        s += v; s2 += v*v;
    }
    for (int off = 32; off > 0; off >>= 1) {
        s  += __shfl_down(s, off);
        s2 += __shfl_down(s2, off);
    }
    __shared__ float r1[4], r2[4];
    int wv = tid >> 6;
    if ((tid & 63) == 0) { r1[wv] = s; r2[wv] = s2; }
    __syncthreads();
    if (tid == 0) {
        float S1 = r1[0]+r1[1]+r1[2]+r1[3];
        float S2 = r2[0]+r2[1]+r2[2]+r2[3];
        const float invN = 1.f/(float)(B_*T_);
        float m = S1*invN;
        float var = S2*invN - m*m;
        float rs = rsqrtf(var + 1e-5f);
        float A = rs * g[ch];
        aff[2*ch]   = A;
        aff[2*ch+1] = bb[ch] - m*A;
    }
}

// ---------------- transpose up_w [512][128] -> [128][512] ----------------
__global__ void k_tr_wu(const float* __restrict__ w, float* __restrict__ wt) {
    __shared__ float tile[32][33];
    int c0 = blockIdx.x*32;   // co
    int i0 = blockIdx.y*32;   // ci
    int tx = threadIdx.x, ty = threadIdx.y;
#pragma unroll
    for (int j = 0; j < 4; ++j)
        tile[ty+j*8][tx] = w[(size_t)(c0+ty+j*8)*CH_ + i0 + tx];
    __syncthreads();
#pragma unroll
    for (int j = 0; j < 4; ++j)
        wt[(size_t)(i0+ty+j*8)*EC_ + c0 + tx] = tile[tx][ty+j*8];
}

// ---------------- up-projection + relu -> enc[t][c] bf16 (single batch) ----------------
__global__ void k_up(const float* __restrict__ a, const float* __restrict__ wt,
                     const float* __restrict__ ub, const float* __restrict__ aff,
                     unsigned short* __restrict__ enc, int b) {
    int tid = threadIdx.x;
    int co = blockIdx.z*128 + tid;
    int t0 = blockIdx.x*16;
    float acc[16];
#pragma unroll
    for (int i = 0; i < 16; ++i) acc[i] = 0.f;
    float bacc = 0.f;
    for (int ci = 0; ci < CH_; ++ci) {
        float wv = wt[(size_t)ci*EC_ + co];
        float A_ = aff[2*ci], Bb_ = aff[2*ci+1];
        const float* ip = a + ((size_t)(b*CH_ + ci))*T_ + t0;
        float wA = wv * A_;
        bacc = fmaf(wv, Bb_, bacc);
#pragma unroll
        for (int tt = 0; tt < 16; ++tt)
            acc[tt] = fmaf(wA, ip[tt], acc[tt]);
    }
    float biasv = ub[co] + bacc;
#pragma unroll
    for (int tt = 0; tt < 16; ++tt) {
        float v = acc[tt] + biasv;
        v = v > 0.f ? v : 0.f;
        enc[((size_t)(t0 + tt))*EC_ + co] = f2bf(v);
    }
}

// ---------------- transpose static_dict [512][2048] fp32 -> At [2048][512] bf16 ----------------
__global__ void k_tr_at(const float* __restrict__ sd, unsigned short* __restrict__ At) {
    __shared__ float tile[32][33];
    int tau0 = blockIdx.x*32;
    int c0 = blockIdx.y*32;
    int tx = threadIdx.x, ty = threadIdx.y;
#pragma unroll
    for (int j = 0; j < 4; ++j)
        tile[ty+j*8][tx] = sd[(size_t)(c0+ty+j*8)*ATOM_ + tau0 + tx];
    __syncthreads();
#pragma unroll
    for (int j = 0; j < 4; ++j)
        At[(size_t)(tau0+ty+j*8)*EC_ + c0 + tx] = f2bf(tile[tx][ty+j*8]);
}

// ---------------- GEMM: Gchunk[512,T] = At_chunk[512,512] x enc^T (bf16 MFMA) ----------------
__global__ void __launch_bounds__(256) k_gemm(const unsigned short* __restrict__ At,
                                              const unsigned short* __restrict__ Et,
                                              unsigned short* __restrict__ G) {
    __shared__ unsigned short lA[128][72];
    __shared__ unsigned short lB[128][72];
    int tid = threadIdx.x;
    int lane = tid & 63;
    int wv = tid >> 6;
    int wm = wv >> 1, wn = wv & 1;
    int sT = blockIdx.x;   // s tiles (T/128)
    int tT = blockIdx.y;   // tau tiles within chunk (4)
    int ln15 = lane & 15, kh = lane >> 4;
    f32x4 acc[4][4];
    f32x4 zero = {0.f, 0.f, 0.f, 0.f};
#pragma unroll
    for (int m = 0; m < 4; ++m)
#pragma unroll
        for (int n = 0; n < 4; ++n) acc[m][n] = zero;

    for (int kt = 0; kt < 8; ++kt) {
#pragma unroll
        for (int r = 0; r < 4; ++r) {
            int idx = tid + r*256;
            int row = idx >> 3, ch = idx & 7;
            s16x8 va = *(const s16x8*)(At + ((size_t)(tT*128+row))*EC_ + kt*64 + ch*8);
            *(s16x8*)&lA[row][ch*8] = va;
            s16x8 vb = *(const s16x8*)(Et + ((size_t)(sT*128+row))*EC_ + kt*64 + ch*8);
            *(s16x8*)&lB[row][ch*8] = vb;
        }
        __syncthreads();
#pragma unroll
        for (int kk = 0; kk < 2; ++kk) {
            s16x8 af[4], bfr[4];
#pragma unroll
            for (int m = 0; m < 4; ++m)
                af[m] = *(const s16x8*)&lA[wm*64 + m*16 + ln15][kk*32 + kh*8];
#pragma unroll
            for (int n = 0; n < 4; ++n)
                bfr[n] = *(const s16x8*)&lB[wn*64 + n*16 + ln15][kk*32 + kh*8];
#pragma unroll
            for (int m = 0; m < 4; ++m)
#pragma unroll
                for (int n = 0; n < 4; ++n)
                    acc[m][n] = __builtin_amdgcn_mfma_f32_16x16x32_bf16(af[m], bfr[n], acc[m][n], 0, 0, 0);
        }
        __syncthreads();
    }
#pragma unroll
    for (int m = 0; m < 4; ++m) {
#pragma unroll
        for (int n = 0; n < 4; ++n) {
            int rowb = tT*128 + wm*64 + m*16 + kh*4;
            int col  = sT*128 + wn*64 + n*16 + ln15;
#pragma unroll
            for (int j = 0; j < 4; ++j)
                G[(size_t)(rowb+j)*T_ + col] = f2bf(acc[m][n][j]);
        }
    }
}

// ---------------- anti-diagonal sum over a 128-row sub-slice of the 512-row chunk ----------------
__global__ void k_diag(const unsigned short* __restrict__ G, float* __restrict__ part, int tau0) {
    int t = blockIdx.x*256 + threadIdx.x;
    int sub = blockIdx.y;            // 0..3
    int lr0 = sub*128;
    float acc = 0.f;
    int lrend = min(128, t + 1 - (tau0 + lr0));   // tau <= t ; tau < 2048 is automatic
    for (int lr = 0; lr < lrend; ++lr) {
        int tau = tau0 + lr0 + lr;
        acc += bf2f(G[(size_t)(lr0 + lr)*T_ + (t - tau)]);
    }
    part[(size_t)sub*T_ + t] = acc;
}

__global__ void k_diag2(const float* __restrict__ part, float* __restrict__ out) {
    int t = blockIdx.x*256 + threadIdx.x;
    float s = 0.f;
#pragma unroll
    for (int i = 0; i < 16; ++i) s += part[(size_t)i*T_ + t];
    out[t] = s;
}

__global__ void k_fill(float* __restrict__ out, float val) {
    out[blockIdx.x*256 + threadIdx.x] = val;
}

extern "C" void kernel_launch(void* const* d_in, const int* in_sizes, int n_in,
                              void* d_out, int out_size, void* d_ws, size_t ws_size,
                              hipStream_t stream) {
    const float* x       = (const float*)d_in[0];
    const float* fb_w    = (const float*)d_in[1];
    const float* conv0_w = (const float*)d_in[2];
    const float* conv0_b = (const float*)d_in[3];
    const float* bn0_g   = (const float*)d_in[4];
    const float* bn0_b   = (const float*)d_in[5];
    const float* dil_w   = (const float*)d_in[6];
    const float* dil_b   = (const float*)d_in[7];
    const float* pw_w    = (const float*)d_in[8];
    const float* pw_b    = (const float*)d_in[9];
    const float* bn_g    = (const float*)d_in[10];
    const float* bn_b    = (const float*)d_in[11];
    const float* up_w    = (const float*)d_in[12];
    const float* up_b    = (const float*)d_in[13];
    const float* sdict   = (const float*)d_in[14];
    float* out = (float*)d_out;
    char* ws = (char*)d_ws;

    const size_t SZ = (size_t)B_*CH_*T_*4;           // 33,554,432 B
    float* bufA = (float*)(ws);                       // later: enc alias
    float* bufB = (float*)(ws + SZ);                  // final activation lives here
    float* tmp  = (float*)(ws + 2*SZ);                // later: G-chunk alias
    unsigned short* At  = (unsigned short*)(ws + 3*SZ);            // 2 MB
    float* Wut = (float*)((char*)At + (size_t)ATOM_*EC_*2);        // 256 KB
    float* aff = (float*)((char*)Wut + (size_t)CH_*EC_*4);         // 8 KB
    float* part = aff + 8*2*CH_;                                   // 16*T*4 = 2 MB
    const size_t TOTAL = 3*SZ + (size_t)ATOM_*EC_*2 + (size_t)CH_*EC_*4
                       + 8*2*CH_*4 + 16*(size_t)T_*4;
    if (ws_size < TOTAL) {                    // diagnostic: distinguishable failure
        k_fill<<<(out_size+255)/256, 256, 0, stream>>>(out, 12345.0f);
        return;
    }
    unsigned short* enc = (unsigned short*)bufA;      // 33,554,432 B (exact alias)
    unsigned short* G   = (unsigned short*)tmp;       // 512*T*2 = 33,554,432 B (exact alias)

    // filter bank -> tmp (spec)
    k_fb<<<dim3(T_/1024, 8, B_), 256, 0, stream>>>(x, fb_w, tmp);
    // conv0 + lrelu -> bufA
    k_conv<7, false, true><<<dim3(T_/64, B_), 256, 0, stream>>>(tmp, conv0_w, conv0_b, nullptr, bufA, 1);
    k_stats<<<128, 256, 0, stream>>>(bufA, bn0_g, bn0_b, aff);

    const int DILS[7] = {1, 3, 9, 27, 81, 243, 1};
    float* cur = bufA; float* nxt = bufB;
    for (int i = 0; i < 7; ++i) {
        k_conv<3, true, false><<<dim3(T_/64, B_), 256, 0, stream>>>(
            cur, dil_w + (size_t)i*CH_*CH_*3, dil_b + i*CH_, aff + i*2*CH_, tmp, DILS[i]);
        k_pw<<<dim3(T_/64, B_), 256, 0, stream>>>(
            tmp, pw_w + (size_t)i*CH_*CH_, pw_b + i*CH_, aff + i*2*CH_, cur, nxt);
        k_stats<<<128, 256, 0, stream>>>(nxt, bn_g + i*CH_, bn_b + i*CH_, aff + (i+1)*2*CH_);
        float* sw = cur; cur = nxt; nxt = sw;
    }
    // cur == bufB here; bufA and tmp are free.

    k_tr_wu<<<dim3(EC_/32, CH_/32), dim3(32, 8), 0, stream>>>(up_w, Wut);
    k_tr_at<<<dim3(ATOM_/32, EC_/32), dim3(32, 8), 0, stream>>>(sdict, At);

    for (int b = 0; b < B_; ++b) {
        k_up<<<dim3(T_/16, 1, EC_/128), 128, 0, stream>>>(cur, Wut, up_b, aff + 7*2*CH_, enc, b);
        for (int cc = 0; cc < 4; ++cc) {
            k_gemm<<<dim3(T_/128, 4), 256, 0, stream>>>(At + (size_t)cc*512*EC_, enc, G);
            k_diag<<<dim3(T_/256, 4), 256, 0, stream>>>(G, part + (size_t)cc*4*T_, cc*512);
        }
        k_diag2<<<T_/256, 256, 0, stream>>>(part, out + (size_t)b*T_);
    }
}

// Round 3
// 1296.965 us; speedup vs baseline: 3.5961x; 3.5961x over previous
//
#include <hip/hip_runtime.h>
#include <hip/hip_bf16.h>

#define B_ 2
#define T_ 32768
#define CH_ 128
#define EC_ 512
#define ATOM_ 2048
#define FBK_ 512

typedef __attribute__((ext_vector_type(8))) short s16x8;
typedef __attribute__((ext_vector_type(8))) _Float16 f16x8;
typedef __attribute__((ext_vector_type(4))) float f32x4;

__device__ __forceinline__ f16x8 ldh8(const _Float16* p) {
    union { s16x8 s; f16x8 h; } u; u.s = *(const s16x8*)p; return u.h;
}

// ---------------- filter bank: x[b,1,T] -> spec32[b,128,T] (band-major fp32) ----------------
__global__ void k_fb(const float* __restrict__ x, const float* __restrict__ fbw,
                     float* __restrict__ spec) {
    __shared__ float xs[1024 + FBK_ + 4];
    int t0 = blockIdx.x * 1024;
    int bg = blockIdx.y;
    int b  = blockIdx.z;
    int tid = threadIdx.x;
    for (int i = tid; i < 1024 + FBK_ + 4; i += 256) {
        int gx = t0 - FBK_/2 + i;
        xs[i] = (gx >= 0 && gx < T_) ? x[(size_t)b*T_ + gx] : 0.f;
    }
    __syncthreads();
    int base = tid * 4;
    for (int bi = 0; bi < 16; ++bi) {
        int band = bg*16 + bi;
        const float* w = fbw + (size_t)band * FBK_;
        float a0=0.f,a1=0.f,a2=0.f,a3=0.f;
        float4 cur = *(const float4*)&xs[base];
        for (int k4 = 0; k4 < FBK_; k4 += 4) {
            float4 nxt = *(const float4*)&xs[base + k4 + 4];
            float w0 = w[k4], w1 = w[k4+1], w2 = w[k4+2], w3 = w[k4+3];
            a0 = fmaf(w0,cur.x,fmaf(w1,cur.y,fmaf(w2,cur.z,fmaf(w3,cur.w,a0))));
            a1 = fmaf(w0,cur.y,fmaf(w1,cur.z,fmaf(w2,cur.w,fmaf(w3,nxt.x,a1))));
            a2 = fmaf(w0,cur.z,fmaf(w1,cur.w,fmaf(w2,nxt.x,fmaf(w3,nxt.y,a2))));
            a3 = fmaf(w0,cur.w,fmaf(w1,nxt.x,fmaf(w2,nxt.y,fmaf(w3,nxt.z,a3))));
            cur = nxt;
        }
        size_t o = ((size_t)(b*CH_ + band))*T_ + t0 + base;
        float4 r; r.x=a0; r.y=a1; r.z=a2; r.w=a3;
        *(float4*)&spec[o] = r;
    }
}

// ---------------- transpose spec32 [b][band][t] -> spec16 [b][t][band] f16 ----------------
__global__ void k_tr_spec(const float* __restrict__ in, _Float16* __restrict__ out) {
    __shared__ float tile[32][33];
    int t0 = blockIdx.x*32, c0 = blockIdx.y*32, b = blockIdx.z;
    const float* ib = in + (size_t)b*CH_*T_;
    _Float16* ob = out + (size_t)b*T_*CH_;
    int tx = threadIdx.x, ty = threadIdx.y;
#pragma unroll
    for (int j = 0; j < 4; ++j)
        tile[ty+j*8][tx] = ib[(size_t)(c0+ty+j*8)*T_ + t0+tx];
    __syncthreads();
#pragma unroll
    for (int j = 0; j < 4; ++j)
        ob[(size_t)(t0+ty+j*8)*CH_ + c0+tx] = (_Float16)tile[tx][ty+j*8];
}

// ---------------- weight prep ----------------
__global__ void k_pw7(const float* __restrict__ w, _Float16* __restrict__ W7) {
    int i = blockIdx.x*256+threadIdx.x;
    if (i >= 7*16384) return;
    int k = i / 16384, r = i % 16384; int co = r >> 7, ci = r & 127;
    W7[i] = (_Float16)w[(co*CH_+ci)*7 + k];
}
__global__ void k_pwd(const float* __restrict__ w, _Float16* __restrict__ Wd) {
    int i = blockIdx.x*256+threadIdx.x;
    if (i >= 7*3*16384) return;
    int st = i / 49152, r = i % 49152; int k = r / 16384, r2 = r % 16384;
    int co = r2 >> 7, ci = r2 & 127;
    Wd[i] = (_Float16)w[((size_t)(st*CH_+co)*CH_+ci)*3 + k];
}
__global__ void k_cast(const float* __restrict__ in, _Float16* __restrict__ out, int n) {
    int i = blockIdx.x*256+threadIdx.x;
    if (i < n) out[i] = (_Float16)in[i];
}
__global__ void k_zero(float* __restrict__ p, int n) {
    int i = blockIdx.x*256+threadIdx.x;
    if (i < n) p[i] = 0.f;
}

// ---------------- fused MFMA conv block ----------------
// Tile: 128 t x 128 co.  A=X[t][ci] (LDS), B=W[co][ci] (LDS), K=ci.
// PW: second GEMM y2 = Wp x y1, + residual (center tap tile) + lrelu + stats.
template<int NTAP, bool NORM, bool PW, bool LRELU, bool RELU, bool STATS>
__global__ void __launch_bounds__(256) k_cv(
        const _Float16* __restrict__ in, const _Float16* __restrict__ W,
        const float* __restrict__ bias, const _Float16* __restrict__ Wp_,
        const float* __restrict__ pbias, const float* __restrict__ stats_in,
        const float* __restrict__ g, const float* __restrict__ bb,
        float* __restrict__ stats_out, _Float16* __restrict__ outp,
        int dil, int ostride) {
    __shared__ _Float16 XT[128][136];
    __shared__ _Float16 WT[128][136];
    __shared__ _Float16 Y1[PW?128:1][PW?136:1];
    __shared__ float AffA[NORM?128:1], AffB[NORM?128:1];

    int tid = threadIdx.x;
    int lane = tid & 63;
    int wv = tid >> 6, wm = wv >> 1, wn = wv & 1;
    int ln15 = lane & 15, kh = lane >> 4;
    int t0 = blockIdx.x * 128;
    int nch = blockIdx.y;
    int b = blockIdx.z;
    int ncol0 = nch * 128;
    const _Float16* inb = in + (size_t)b*T_*CH_;
    const _Float16* W_eff = W + (size_t)ncol0*CH_;
    const float* bias_eff = bias + ncol0;

    if (NORM) {
        if (tid < 128) {
            const float invN = 1.f/(float)(B_*T_);
            float s1 = stats_in[tid], s2 = stats_in[128+tid];
            float m = s1*invN, var = s2*invN - m*m;
            float A = rsqrtf(var + 1e-5f) * g[tid];
            AffA[tid] = A; AffB[tid] = bb[tid] - m*A;
        }
        __syncthreads();
    }

    f32x4 acc[4][4];
    f32x4 zero = {0.f,0.f,0.f,0.f};
#pragma unroll
    for (int m = 0; m < 4; ++m)
#pragma unroll
        for (int n = 0; n < 4; ++n) acc[m][n] = zero;

    for (int tap = 0; tap < NTAP; ++tap) {
        int tp = tap;
        if (PW) tp = (tap==0) ? 0 : ((tap==1) ? 2 : 1);   // center tap LAST (kept for residual)
        int off = (tp - NTAP/2)*dil;
        const _Float16* Wt = W_eff + (size_t)tp*CH_*CH_;
#pragma unroll
        for (int q = 0; q < 8; ++q) {
            int idx = tid + q*256;
            int lt = idx >> 4, ck = idx & 15;
            int gt = t0 + lt + off;
            s16x8 v = {0,0,0,0,0,0,0,0};
            bool valid = (gt >= 0 && gt < T_);
            if (valid) {
                v = *(const s16x8*)(inb + (size_t)gt*CH_ + ck*8);
                if (NORM) {
                    union {s16x8 s; f16x8 h;} u; u.s = v;
                    f16x8 r;
#pragma unroll
                    for (int j = 0; j < 8; ++j) {
                        float f = (float)u.h[j];
                        f = fmaf(f, AffA[ck*8+j], AffB[ck*8+j]);
                        r[j] = (_Float16)f;
                    }
                    union {f16x8 h; s16x8 s;} w2; w2.h = r; v = w2.s;
                }
            }
            *(s16x8*)&XT[lt][ck*8] = v;
            *(s16x8*)&WT[lt][ck*8] = *(const s16x8*)(Wt + (size_t)lt*CH_ + ck*8);
        }
        __syncthreads();
#pragma unroll
        for (int kt = 0; kt < 4; ++kt) {
            f16x8 af[4], bf[4];
#pragma unroll
            for (int m = 0; m < 4; ++m) af[m] = ldh8(&XT[wm*64+m*16+ln15][kt*32+kh*8]);
#pragma unroll
            for (int n = 0; n < 4; ++n) bf[n] = ldh8(&WT[wn*64+n*16+ln15][kt*32+kh*8]);
#pragma unroll
            for (int m = 0; m < 4; ++m)
#pragma unroll
                for (int n = 0; n < 4; ++n)
                    acc[m][n] = __builtin_amdgcn_mfma_f32_16x16x32_f16(af[m], bf[n], acc[m][n], 0,0,0);
        }
        __syncthreads();
    }

    if (PW) {
        // y1 (+dil bias) -> LDS f16
#pragma unroll
        for (int mf = 0; mf < 4; ++mf)
#pragma unroll
            for (int nf = 0; nf < 4; ++nf) {
                int co = wn*64 + nf*16 + ln15;
                float bv = bias_eff[co];
#pragma unroll
                for (int j = 0; j < 4; ++j) {
                    int tl = wm*64 + mf*16 + kh*4 + j;
                    Y1[tl][co] = (_Float16)(acc[mf][nf][j] + bv);
                }
            }
        __syncthreads();
#pragma unroll
        for (int q = 0; q < 8; ++q) {
            int idx = tid + q*256;
            int lt = idx >> 4, ck = idx & 15;
            *(s16x8*)&WT[lt][ck*8] = *(const s16x8*)(Wp_ + (size_t)lt*CH_ + ck*8);
        }
#pragma unroll
        for (int m = 0; m < 4; ++m)
#pragma unroll
            for (int n = 0; n < 4; ++n) acc[m][n] = zero;
        __syncthreads();
#pragma unroll
        for (int kt = 0; kt < 4; ++kt) {
            f16x8 af[4], bf[4];
#pragma unroll
            for (int m = 0; m < 4; ++m) af[m] = ldh8(&Y1[wm*64+m*16+ln15][kt*32+kh*8]);
#pragma unroll
            for (int n = 0; n < 4; ++n) bf[n] = ldh8(&WT[wn*64+n*16+ln15][kt*32+kh*8]);
#pragma unroll
            for (int m = 0; m < 4; ++m)
#pragma unroll
                for (int n = 0; n < 4; ++n)
                    acc[m][n] = __builtin_amdgcn_mfma_f32_16x16x32_f16(af[m], bf[n], acc[m][n], 0,0,0);
        }
    }

    // epilogue: bias (+residual) (+act) + write + stats
#pragma unroll
    for (int nf = 0; nf < 4; ++nf) {
        int co = wn*64 + nf*16 + ln15;
        float bfin = PW ? pbias[co] : bias_eff[co];
        float s = 0.f, s2 = 0.f;
#pragma unroll
        for (int mf = 0; mf < 4; ++mf) {
#pragma unroll
            for (int j = 0; j < 4; ++j) {
                int tl = wm*64 + mf*16 + kh*4 + j;
                float v = acc[mf][nf][j] + bfin;
                if (PW) v += (float)XT[tl][co];     // residual = normalized center tile
                if (LRELU) v = v >= 0.f ? v : 0.2f*v;
                if (RELU)  v = fmaxf(v, 0.f);
                outp[((size_t)b*T_ + t0 + tl)*ostride + ncol0 + co] = (_Float16)v;
                if (STATS) { s += v; s2 += v*v; }
            }
        }
        if (STATS) {
            s  += __shfl_down(s, 16);  s  += __shfl_down(s, 32);
            s2 += __shfl_down(s2, 16); s2 += __shfl_down(s2, 32);
            if (kh == 0) {
                atomicAdd(&stats_out[co], s);
                atomicAdd(&stats_out[128+co], s2);
            }
        }
    }
}

// ---------------- transpose static_dict [512][2048] fp32 -> At [2048][512] f16 ----------------
__global__ void k_tr_at(const float* __restrict__ sd, _Float16* __restrict__ At) {
    __shared__ float tile[32][33];
    int tau0 = blockIdx.x*32;
    int c0 = blockIdx.y*32;
    int tx = threadIdx.x, ty = threadIdx.y;
#pragma unroll
    for (int j = 0; j < 4; ++j)
        tile[ty+j*8][tx] = sd[(size_t)(c0+ty+j*8)*ATOM_ + tau0 + tx];
    __syncthreads();
#pragma unroll
    for (int j = 0; j < 4; ++j)
        At[(size_t)(tau0+ty+j*8)*EC_ + c0 + tx] = (_Float16)tile[tx][ty+j*8];
}

// ---------------- GEMM: Gchunk[512,T] = At_chunk[512,512] x enc^T (f16 MFMA) ----------------
__global__ void __launch_bounds__(256) k_gemm(const _Float16* __restrict__ At,
                                              const _Float16* __restrict__ Et,
                                              _Float16* __restrict__ G) {
    __shared__ _Float16 lA[128][72];
    __shared__ _Float16 lB[128][72];
    int tid = threadIdx.x;
    int lane = tid & 63;
    int wv = tid >> 6;
    int wm = wv >> 1, wn = wv & 1;
    int sT = blockIdx.x;
    int tT = blockIdx.y;
    int ln15 = lane & 15, kh = lane >> 4;
    f32x4 acc[4][4];
    f32x4 zero = {0.f,0.f,0.f,0.f};
#pragma unroll
    for (int m = 0; m < 4; ++m)
#pragma unroll
        for (int n = 0; n < 4; ++n) acc[m][n] = zero;

    for (int kt = 0; kt < 8; ++kt) {
#pragma unroll
        for (int r = 0; r < 4; ++r) {
            int idx = tid + r*256;
            int row = idx >> 3, ch = idx & 7;
            *(s16x8*)&lA[row][ch*8] = *(const s16x8*)(At + ((size_t)(tT*128+row))*EC_ + kt*64 + ch*8);
            *(s16x8*)&lB[row][ch*8] = *(const s16x8*)(Et + ((size_t)(sT*128+row))*EC_ + kt*64 + ch*8);
        }
        __syncthreads();
#pragma unroll
        for (int kk = 0; kk < 2; ++kk) {
            f16x8 af[4], bfr[4];
#pragma unroll
            for (int m = 0; m < 4; ++m)
                af[m] = ldh8(&lA[wm*64 + m*16 + ln15][kk*32 + kh*8]);
#pragma unroll
            for (int n = 0; n < 4; ++n)
                bfr[n] = ldh8(&lB[wn*64 + n*16 + ln15][kk*32 + kh*8]);
#pragma unroll
            for (int m = 0; m < 4; ++m)
#pragma unroll
                for (int n = 0; n < 4; ++n)
                    acc[m][n] = __builtin_amdgcn_mfma_f32_16x16x32_f16(af[m], bfr[n], acc[m][n], 0, 0, 0);
        }
        __syncthreads();
    }
#pragma unroll
    for (int m = 0; m < 4; ++m) {
#pragma unroll
        for (int n = 0; n < 4; ++n) {
            int rowb = tT*128 + wm*64 + m*16 + kh*4;
            int col  = sT*128 + wn*64 + n*16 + ln15;
#pragma unroll
            for (int j = 0; j < 4; ++j)
                G[(size_t)(rowb+j)*T_ + col] = (_Float16)acc[m][n][j];
        }
    }
}

// ---------------- anti-diagonal sum ----------------
__global__ void k_diag(const _Float16* __restrict__ G, float* __restrict__ part, int tau0) {
    int t = blockIdx.x*256 + threadIdx.x;
    int sub = blockIdx.y;
    int lr0 = sub*128;
    float acc = 0.f;
    int lrend = min(128, t + 1 - (tau0 + lr0));
    for (int lr = 0; lr < lrend; ++lr) {
        int tau = tau0 + lr0 + lr;
        acc += (float)G[(size_t)(lr0 + lr)*T_ + (t - tau)];
    }
    part[(size_t)sub*T_ + t] = acc;
}

__global__ void k_diag2(const float* __restrict__ part, float* __restrict__ out) {
    int t = blockIdx.x*256 + threadIdx.x;
    float s = 0.f;
#pragma unroll
    for (int i = 0; i < 16; ++i) s += part[(size_t)i*T_ + t];
    out[t] = s;
}

__global__ void k_fill(float* __restrict__ out, float val) {
    out[blockIdx.x*256 + threadIdx.x] = val;
}

extern "C" void kernel_launch(void* const* d_in, const int* in_sizes, int n_in,
                              void* d_out, int out_size, void* d_ws, size_t ws_size,
                              hipStream_t stream) {
    const float* x       = (const float*)d_in[0];
    const float* fb_w    = (const float*)d_in[1];
    const float* conv0_w = (const float*)d_in[2];
    const float* conv0_b = (const float*)d_in[3];
    const float* bn0_g   = (const float*)d_in[4];
    const float* bn0_b   = (const float*)d_in[5];
    const float* dil_w   = (const float*)d_in[6];
    const float* dil_b   = (const float*)d_in[7];
    const float* pw_w    = (const float*)d_in[8];
    const float* pw_b    = (const float*)d_in[9];
    const float* bn_g    = (const float*)d_in[10];
    const float* bn_b    = (const float*)d_in[11];
    const float* up_w    = (const float*)d_in[12];
    const float* up_b    = (const float*)d_in[13];
    const float* sdict   = (const float*)d_in[14];
    float* out = (float*)d_out;
    char* ws = (char*)d_ws;

    // layout (bytes)
    const size_t R1   = 33554432;   // spec32 (fp32 band-major) -> later enc (f16, per-b)
    const size_t R2   = 33554432;   // spec16 (f16 time-major, 16.8MB) -> later G (f16, 33.5MB)
    const size_t ACT  = 16777216;   // f16 [b][t][c]
    char* r1   = ws;
    char* r2   = ws + R1;
    char* actA = ws + R1 + R2;
    char* actB = actA + ACT;
    char* wreg = actB + ACT;
    _Float16* W7  = (_Float16*)wreg;                       // 7*16384
    _Float16* Wd  = W7 + 7*16384;                          // 7*3*16384
    _Float16* Wp  = Wd + 7*3*16384;                        // 7*16384
    _Float16* Wup = Wp + 7*16384;                          // 65536
    float* stats  = (float*)(Wup + 65536);                 // 8*2*128 floats
    const size_t TOTAL = R1 + R2 + 2*ACT
                       + (7*16384 + 7*3*16384 + 7*16384 + 65536)*2 + 8*2*128*4;
    if (ws_size < TOTAL) {
        k_fill<<<(out_size+255)/256, 256, 0, stream>>>(out, 12345.0f);
        return;
    }
    float* spec32 = (float*)r1;
    _Float16* spec16 = (_Float16*)r2;
    _Float16* enc = (_Float16*)r1;            // alias (spec32 dead)
    _Float16* G   = (_Float16*)r2;            // alias (spec16 dead)
    float* part   = (float*)actA;             // alias after last block (2MB)
    _Float16* At  = (_Float16*)(actA + 2097152);  // alias (2MB)

    // prep
    k_zero<<<(2048+255)/256, 256, 0, stream>>>(stats, 8*2*128);
    k_pw7<<<(7*16384+255)/256, 256, 0, stream>>>(conv0_w, W7);
    k_pwd<<<(7*3*16384+255)/256, 256, 0, stream>>>(dil_w, Wd);
    k_cast<<<(7*16384+255)/256, 256, 0, stream>>>(pw_w, Wp, 7*16384);
    k_cast<<<(65536+255)/256, 256, 0, stream>>>(up_w, Wup, 65536);

    // front
    k_fb<<<dim3(T_/1024, 8, B_), 256, 0, stream>>>(x, fb_w, spec32);
    k_tr_spec<<<dim3(T_/32, CH_/32, B_), dim3(32,8), 0, stream>>>(spec32, spec16);
    k_cv<7,false,false,true,false,true><<<dim3(T_/128,1,B_), 256, 0, stream>>>(
        spec16, W7, conv0_b, nullptr, nullptr, nullptr, nullptr, nullptr,
        stats + 0, (_Float16*)actA, 1, CH_);

    const int DILS[7] = {1, 3, 9, 27, 81, 243, 1};
    _Float16* cur = (_Float16*)actA;
    _Float16* nxt = (_Float16*)actB;
    for (int i = 0; i < 7; ++i) {
        const float* gi = (i == 0) ? bn0_g : bn_g + (i-1)*CH_;
        const float* bi = (i == 0) ? bn0_b : bn_b + (i-1)*CH_;
        k_cv<3,true,true,true,false,true><<<dim3(T_/128,1,B_), 256, 0, stream>>>(
            cur, Wd + (size_t)i*3*CH_*CH_, dil_b + i*CH_, Wp + (size_t)i*CH_*CH_,
            pw_b + i*CH_, stats + i*256, gi, bi, stats + (i+1)*256, nxt, DILS[i], CH_);
        _Float16* sw = cur; cur = nxt; nxt = sw;
    }
    // cur == actB; actA free -> part/At aliases valid from here
    k_tr_at<<<dim3(ATOM_/32, EC_/32), dim3(32,8), 0, stream>>>(sdict, At);

    for (int b = 0; b < B_; ++b) {
        k_cv<1,true,false,false,true,false><<<dim3(T_/128,EC_/128,1), 256, 0, stream>>>(
            cur + (size_t)b*T_*CH_, Wup, up_b, nullptr, nullptr,
            stats + 7*256, bn_g + 6*CH_, bn_b + 6*CH_, nullptr, enc, 1, EC_);
        for (int cc = 0; cc < 4; ++cc) {
            k_gemm<<<dim3(T_/128, 4), 256, 0, stream>>>(At + (size_t)cc*512*EC_, enc, G);
            k_diag<<<dim3(T_/256, 4), 256, 0, stream>>>(G, part + (size_t)cc*4*T_, cc*512);
        }
        k_diag2<<<T_/256, 256, 0, stream>>>(part, out + (size_t)b*T_);
    }
}

// Round 4
// 1047.757 us; speedup vs baseline: 4.4515x; 1.2378x over previous
//
#include <hip/hip_runtime.h>
#include <hip/hip_bf16.h>

#define B_ 2
#define T_ 32768
#define CH_ 128
#define EC_ 512
#define ATOM_ 2048
#define FBK_ 512

typedef __attribute__((ext_vector_type(8))) short s16x8;
typedef __attribute__((ext_vector_type(8))) _Float16 f16x8;
typedef __attribute__((ext_vector_type(4))) float f32x4;

__device__ __forceinline__ f16x8 ldh8(const _Float16* p) {
    union { s16x8 s; f16x8 h; } u; u.s = *(const s16x8*)p; return u.h;
}

// ---------------- MFMA filter bank: x[b,1,T] -> spec16[b][t][band] f16 ----------------
// spec[t][band] = sum_k x[t+k-256] * w[band][k]   (Toeplitz A from LDS x-window)
__global__ void __launch_bounds__(256) k_fbm(const float* __restrict__ x,
        const _Float16* __restrict__ Wfb, _Float16* __restrict__ spec16) {
    __shared__ _Float16 XA[128][72];
    __shared__ _Float16 WT[128][72];
    __shared__ float xw[640];
    int tid = threadIdx.x;
    int lane = tid & 63;
    int wv = tid >> 6, wm = wv >> 1, wn = wv & 1;
    int ln15 = lane & 15, kh = lane >> 4;
    int t0 = blockIdx.x * 128;
    int b = blockIdx.y;

    for (int i = tid; i < 640; i += 256) {
        int g = t0 - 256 + i;
        xw[i] = (g >= 0 && g < T_) ? x[(size_t)b*T_ + g] : 0.f;
    }

    f32x4 acc[4][4];
    f32x4 zero = {0.f,0.f,0.f,0.f};
#pragma unroll
    for (int m = 0; m < 4; ++m)
#pragma unroll
        for (int n = 0; n < 4; ++n) acc[m][n] = zero;

    for (int c = 0; c < 8; ++c) {
        int k0 = c*64;
        __syncthreads();               // covers xw on c==0, XA/WT reuse on c>0
#pragma unroll
        for (int q = 0; q < 4; ++q) {
            int idx = tid + q*256;     // 1024 = 128 rows x 8 octs
            int r = idx >> 3, ko = idx & 7;
            int base = r + k0 + ko*8;
            f16x8 v;
#pragma unroll
            for (int j = 0; j < 8; ++j) v[j] = (_Float16)xw[base + j];
            union { f16x8 h; s16x8 s; } u; u.h = v;
            *(s16x8*)&XA[r][ko*8] = u.s;
            *(s16x8*)&WT[r][ko*8] = *(const s16x8*)(Wfb + (size_t)r*FBK_ + k0 + ko*8);
        }
        __syncthreads();
#pragma unroll
        for (int kt = 0; kt < 2; ++kt) {
            f16x8 af[4], bf[4];
#pragma unroll
            for (int m = 0; m < 4; ++m) af[m] = ldh8(&XA[wm*64+m*16+ln15][kt*32+kh*8]);
#pragma unroll
            for (int n = 0; n < 4; ++n) bf[n] = ldh8(&WT[wn*64+n*16+ln15][kt*32+kh*8]);
#pragma unroll
            for (int m = 0; m < 4; ++m)
#pragma unroll
                for (int n = 0; n < 4; ++n)
                    acc[m][n] = __builtin_amdgcn_mfma_f32_16x16x32_f16(af[m], bf[n], acc[m][n], 0,0,0);
        }
    }
#pragma unroll
    for (int mf = 0; mf < 4; ++mf)
#pragma unroll
        for (int nf = 0; nf < 4; ++nf) {
            int band = wn*64 + nf*16 + ln15;
#pragma unroll
            for (int j = 0; j < 4; ++j) {
                int tl = wm*64 + mf*16 + kh*4 + j;
                spec16[((size_t)b*T_ + t0 + tl)*CH_ + band] = (_Float16)acc[mf][nf][j];
            }
        }
}

// ---------------- weight prep ----------------
__global__ void k_pw7(const float* __restrict__ w, _Float16* __restrict__ W7) {
    int i = blockIdx.x*256+threadIdx.x;
    if (i >= 7*16384) return;
    int k = i / 16384, r = i % 16384; int co = r >> 7, ci = r & 127;
    W7[i] = (_Float16)w[(co*CH_+ci)*7 + k];
}
__global__ void k_pwd(const float* __restrict__ w, _Float16* __restrict__ Wd) {
    int i = blockIdx.x*256+threadIdx.x;
    if (i >= 7*3*16384) return;
    int st = i / 49152, r = i % 49152; int k = r / 16384, r2 = r % 16384;
    int co = r2 >> 7, ci = r2 & 127;
    Wd[i] = (_Float16)w[((size_t)(st*CH_+co)*CH_+ci)*3 + k];
}
__global__ void k_cast(const float* __restrict__ in, _Float16* __restrict__ out, int n) {
    int i = blockIdx.x*256+threadIdx.x;
    if (i < n) out[i] = (_Float16)in[i];
}
__global__ void k_zero(float* __restrict__ p, int n) {
    int i = blockIdx.x*256+threadIdx.x;
    if (i < n) p[i] = 0.f;
}

// ---------------- fused MFMA conv block ----------------
template<int NTAP, bool NORM, bool PW, bool LRELU, bool RELU, bool STATS>
__global__ void __launch_bounds__(256) k_cv(
        const _Float16* __restrict__ in, const _Float16* __restrict__ W,
        const float* __restrict__ bias, const _Float16* __restrict__ Wp_,
        const float* __restrict__ pbias, const float* __restrict__ stats_in,
        const float* __restrict__ g, const float* __restrict__ bb,
        float* __restrict__ stats_out, _Float16* __restrict__ outp,
        int dil, int ostride) {
    __shared__ _Float16 XT[128][136];
    __shared__ _Float16 WT[128][136];
    __shared__ _Float16 Y1[PW?128:1][PW?136:1];
    __shared__ float AffA[NORM?128:1], AffB[NORM?128:1];

    int tid = threadIdx.x;
    int lane = tid & 63;
    int wv = tid >> 6, wm = wv >> 1, wn = wv & 1;
    int ln15 = lane & 15, kh = lane >> 4;
    int t0 = blockIdx.x * 128;
    int nch = blockIdx.y;
    int b = blockIdx.z;
    int ncol0 = nch * 128;
    const _Float16* inb = in + (size_t)b*T_*CH_;
    const _Float16* W_eff = W + (size_t)ncol0*CH_;
    const float* bias_eff = bias + ncol0;

    if (NORM) {
        if (tid < 128) {
            const float invN = 1.f/(float)(B_*T_);
            float s1 = stats_in[tid], s2 = stats_in[128+tid];
            float m = s1*invN, var = s2*invN - m*m;
            float A = rsqrtf(var + 1e-5f) * g[tid];
            AffA[tid] = A; AffB[tid] = bb[tid] - m*A;
        }
        __syncthreads();
    }

    f32x4 acc[4][4];
    f32x4 zero = {0.f,0.f,0.f,0.f};
#pragma unroll
    for (int m = 0; m < 4; ++m)
#pragma unroll
        for (int n = 0; n < 4; ++n) acc[m][n] = zero;

    for (int tap = 0; tap < NTAP; ++tap) {
        int tp = tap;
        if (PW) tp = (tap==0) ? 0 : ((tap==1) ? 2 : 1);   // center tap LAST (kept for residual)
        int off = (tp - NTAP/2)*dil;
        const _Float16* Wt = W_eff + (size_t)tp*CH_*CH_;
#pragma unroll
        for (int q = 0; q < 8; ++q) {
            int idx = tid + q*256;
            int lt = idx >> 4, ck = idx & 15;
            int gt = t0 + lt + off;
            s16x8 v = {0,0,0,0,0,0,0,0};
            bool valid = (gt >= 0 && gt < T_);
            if (valid) {
                v = *(const s16x8*)(inb + (size_t)gt*CH_ + ck*8);
                if (NORM) {
                    union {s16x8 s; f16x8 h;} u; u.s = v;
                    f16x8 r;
#pragma unroll
                    for (int j = 0; j < 8; ++j) {
                        float f = (float)u.h[j];
                        f = fmaf(f, AffA[ck*8+j], AffB[ck*8+j]);
                        r[j] = (_Float16)f;
                    }
                    union {f16x8 h; s16x8 s;} w2; w2.h = r; v = w2.s;
                }
            }
            *(s16x8*)&XT[lt][ck*8] = v;
            *(s16x8*)&WT[lt][ck*8] = *(const s16x8*)(Wt + (size_t)lt*CH_ + ck*8);
        }
        __syncthreads();
#pragma unroll
        for (int kt = 0; kt < 4; ++kt) {
            f16x8 af[4], bf[4];
#pragma unroll
            for (int m = 0; m < 4; ++m) af[m] = ldh8(&XT[wm*64+m*16+ln15][kt*32+kh*8]);
#pragma unroll
            for (int n = 0; n < 4; ++n) bf[n] = ldh8(&WT[wn*64+n*16+ln15][kt*32+kh*8]);
#pragma unroll
            for (int m = 0; m < 4; ++m)
#pragma unroll
                for (int n = 0; n < 4; ++n)
                    acc[m][n] = __builtin_amdgcn_mfma_f32_16x16x32_f16(af[m], bf[n], acc[m][n], 0,0,0);
        }
        __syncthreads();
    }

    if (PW) {
#pragma unroll
        for (int mf = 0; mf < 4; ++mf)
#pragma unroll
            for (int nf = 0; nf < 4; ++nf) {
                int co = wn*64 + nf*16 + ln15;
                float bv = bias_eff[co];
#pragma unroll
                for (int j = 0; j < 4; ++j) {
                    int tl = wm*64 + mf*16 + kh*4 + j;
                    Y1[tl][co] = (_Float16)(acc[mf][nf][j] + bv);
                }
            }
        __syncthreads();
#pragma unroll
        for (int q = 0; q < 8; ++q) {
            int idx = tid + q*256;
            int lt = idx >> 4, ck = idx & 15;
            *(s16x8*)&WT[lt][ck*8] = *(const s16x8*)(Wp_ + (size_t)lt*CH_ + ck*8);
        }
#pragma unroll
        for (int m = 0; m < 4; ++m)
#pragma unroll
            for (int n = 0; n < 4; ++n) acc[m][n] = zero;
        __syncthreads();
#pragma unroll
        for (int kt = 0; kt < 4; ++kt) {
            f16x8 af[4], bf[4];
#pragma unroll
            for (int m = 0; m < 4; ++m) af[m] = ldh8(&Y1[wm*64+m*16+ln15][kt*32+kh*8]);
#pragma unroll
            for (int n = 0; n < 4; ++n) bf[n] = ldh8(&WT[wn*64+n*16+ln15][kt*32+kh*8]);
#pragma unroll
            for (int m = 0; m < 4; ++m)
#pragma unroll
                for (int n = 0; n < 4; ++n)
                    acc[m][n] = __builtin_amdgcn_mfma_f32_16x16x32_f16(af[m], bf[n], acc[m][n], 0,0,0);
        }
    }

#pragma unroll
    for (int nf = 0; nf < 4; ++nf) {
        int co = wn*64 + nf*16 + ln15;
        float bfin = PW ? pbias[co] : bias_eff[co];
        float s = 0.f, s2 = 0.f;
#pragma unroll
        for (int mf = 0; mf < 4; ++mf) {
#pragma unroll
            for (int j = 0; j < 4; ++j) {
                int tl = wm*64 + mf*16 + kh*4 + j;
                float v = acc[mf][nf][j] + bfin;
                if (PW) v += (float)XT[tl][co];
                if (LRELU) v = v >= 0.f ? v : 0.2f*v;
                if (RELU)  v = fmaxf(v, 0.f);
                outp[((size_t)b*T_ + t0 + tl)*ostride + ncol0 + co] = (_Float16)v;
                if (STATS) { s += v; s2 += v*v; }
            }
        }
        if (STATS) {
            s  += __shfl_down(s, 16);  s  += __shfl_down(s, 32);
            s2 += __shfl_down(s2, 16); s2 += __shfl_down(s2, 32);
            if (kh == 0) {
                atomicAdd(&stats_out[co], s);
                atomicAdd(&stats_out[128+co], s2);
            }
        }
    }
}

// ---------------- transpose static_dict [512][2048] fp32 -> At [2048][512] f16 ----------------
__global__ void k_tr_at(const float* __restrict__ sd, _Float16* __restrict__ At) {
    __shared__ float tile[32][33];
    int tau0 = blockIdx.x*32;
    int c0 = blockIdx.y*32;
    int tx = threadIdx.x, ty = threadIdx.y;
#pragma unroll
    for (int j = 0; j < 4; ++j)
        tile[ty+j*8][tx] = sd[(size_t)(c0+ty+j*8)*ATOM_ + tau0 + tx];
    __syncthreads();
#pragma unroll
    for (int j = 0; j < 4; ++j)
        At[(size_t)(tau0+ty+j*8)*EC_ + c0 + tx] = (_Float16)tile[tx][ty+j*8];
}

// ---------------- GEMM: Gchunk[512,T] = At_chunk[512,512] x enc^T (f16 MFMA) ----------------
__global__ void __launch_bounds__(256) k_gemm(const _Float16* __restrict__ At,
                                              const _Float16* __restrict__ Et,
                                              _Float16* __restrict__ G) {
    __shared__ _Float16 lA[128][72];
    __shared__ _Float16 lB[128][72];
    int tid = threadIdx.x;
    int lane = tid & 63;
    int wv = tid >> 6;
    int wm = wv >> 1, wn = wv & 1;
    int sT = blockIdx.x;
    int tT = blockIdx.y;
    int ln15 = lane & 15, kh = lane >> 4;
    f32x4 acc[4][4];
    f32x4 zero = {0.f,0.f,0.f,0.f};
#pragma unroll
    for (int m = 0; m < 4; ++m)
#pragma unroll
        for (int n = 0; n < 4; ++n) acc[m][n] = zero;

    for (int kt = 0; kt < 8; ++kt) {
#pragma unroll
        for (int r = 0; r < 4; ++r) {
            int idx = tid + r*256;
            int row = idx >> 3, ch = idx & 7;
            *(s16x8*)&lA[row][ch*8] = *(const s16x8*)(At + ((size_t)(tT*128+row))*EC_ + kt*64 + ch*8);
            *(s16x8*)&lB[row][ch*8] = *(const s16x8*)(Et + ((size_t)(sT*128+row))*EC_ + kt*64 + ch*8);
        }
        __syncthreads();
#pragma unroll
        for (int kk = 0; kk < 2; ++kk) {
            f16x8 af[4], bfr[4];
#pragma unroll
            for (int m = 0; m < 4; ++m)
                af[m] = ldh8(&lA[wm*64 + m*16 + ln15][kk*32 + kh*8]);
#pragma unroll
            for (int n = 0; n < 4; ++n)
                bfr[n] = ldh8(&lB[wn*64 + n*16 + ln15][kk*32 + kh*8]);
#pragma unroll
            for (int m = 0; m < 4; ++m)
#pragma unroll
                for (int n = 0; n < 4; ++n)
                    acc[m][n] = __builtin_amdgcn_mfma_f32_16x16x32_f16(af[m], bfr[n], acc[m][n], 0, 0, 0);
        }
        __syncthreads();
    }
#pragma unroll
    for (int m = 0; m < 4; ++m) {
#pragma unroll
        for (int n = 0; n < 4; ++n) {
            int rowb = tT*128 + wm*64 + m*16 + kh*4;
            int col  = sT*128 + wn*64 + n*16 + ln15;
#pragma unroll
            for (int j = 0; j < 4; ++j)
                G[(size_t)(rowb+j)*T_ + col] = (_Float16)acc[m][n][j];
        }
    }
}

// ---------------- anti-diagonal sum ----------------
__global__ void k_diag(const _Float16* __restrict__ G, float* __restrict__ part, int tau0) {
    int t = blockIdx.x*256 + threadIdx.x;
    int sub = blockIdx.y;
    int lr0 = sub*128;
    float acc = 0.f;
    int lrend = min(128, t + 1 - (tau0 + lr0));
    for (int lr = 0; lr < lrend; ++lr) {
        int tau = tau0 + lr0 + lr;
        acc += (float)G[(size_t)(lr0 + lr)*T_ + (t - tau)];
    }
    part[(size_t)sub*T_ + t] = acc;
}

__global__ void k_diag2(const float* __restrict__ part, float* __restrict__ out) {
    int t = blockIdx.x*256 + threadIdx.x;
    float s = 0.f;
#pragma unroll
    for (int i = 0; i < 16; ++i) s += part[(size_t)i*T_ + t];
    out[t] = s;
}

__global__ void k_fill(float* __restrict__ out, float val) {
    out[blockIdx.x*256 + threadIdx.x] = val;
}

extern "C" void kernel_launch(void* const* d_in, const int* in_sizes, int n_in,
                              void* d_out, int out_size, void* d_ws, size_t ws_size,
                              hipStream_t stream) {
    const float* x       = (const float*)d_in[0];
    const float* fb_w    = (const float*)d_in[1];
    const float* conv0_w = (const float*)d_in[2];
    const float* conv0_b = (const float*)d_in[3];
    const float* bn0_g   = (const float*)d_in[4];
    const float* bn0_b   = (const float*)d_in[5];
    const float* dil_w   = (const float*)d_in[6];
    const float* dil_b   = (const float*)d_in[7];
    const float* pw_w    = (const float*)d_in[8];
    const float* pw_b    = (const float*)d_in[9];
    const float* bn_g    = (const float*)d_in[10];
    const float* bn_b    = (const float*)d_in[11];
    const float* up_w    = (const float*)d_in[12];
    const float* up_b    = (const float*)d_in[13];
    const float* sdict   = (const float*)d_in[14];
    float* out = (float*)d_out;
    char* ws = (char*)d_ws;

    // layout (bytes)
    const size_t R1   = 33554432;   // enc (f16, per-b)
    const size_t R2   = 33554432;   // spec16 (f16 time-major, 16.8MB) -> later G (f16, 33.5MB)
    const size_t ACT  = 16777216;   // f16 [b][t][c]
    char* r1   = ws;
    char* r2   = ws + R1;
    char* actA = ws + R1 + R2;
    char* actB = actA + ACT;
    char* wreg = actB + ACT;
    _Float16* W7   = (_Float16*)wreg;                      // 7*16384
    _Float16* Wd   = W7 + 7*16384;                         // 7*3*16384
    _Float16* Wp   = Wd + 7*3*16384;                       // 7*16384
    _Float16* Wup  = Wp + 7*16384;                         // 65536
    _Float16* Wfb  = Wup + 65536;                          // 65536 (fb weights f16)
    float* stats   = (float*)(Wfb + 65536);                // 8*2*128 floats
    const size_t TOTAL = R1 + R2 + 2*ACT
                       + (7*16384 + 7*3*16384 + 7*16384 + 65536 + 65536)*2 + 8*2*128*4;
    if (ws_size < TOTAL) {
        k_fill<<<(out_size+255)/256, 256, 0, stream>>>(out, 12345.0f);
        return;
    }
    _Float16* spec16 = (_Float16*)r2;
    _Float16* enc = (_Float16*)r1;
    _Float16* G   = (_Float16*)r2;            // alias (spec16 dead by then)
    float* part   = (float*)actA;             // alias after last block (2MB)
    _Float16* At  = (_Float16*)(actA + 2097152);  // alias (2MB)

    // prep
    k_zero<<<(2048+255)/256, 256, 0, stream>>>(stats, 8*2*128);
    k_pw7<<<(7*16384+255)/256, 256, 0, stream>>>(conv0_w, W7);
    k_pwd<<<(7*3*16384+255)/256, 256, 0, stream>>>(dil_w, Wd);
    k_cast<<<(7*16384+255)/256, 256, 0, stream>>>(pw_w, Wp, 7*16384);
    k_cast<<<(65536+255)/256, 256, 0, stream>>>(up_w, Wup, 65536);
    k_cast<<<(65536+255)/256, 256, 0, stream>>>(fb_w, Wfb, 65536);

    // front: MFMA filter bank, direct time-major f16
    k_fbm<<<dim3(T_/128, B_), 256, 0, stream>>>(x, Wfb, spec16);
    k_cv<7,false,false,true,false,true><<<dim3(T_/128,1,B_), 256, 0, stream>>>(
        spec16, W7, conv0_b, nullptr, nullptr, nullptr, nullptr, nullptr,
        stats + 0, (_Float16*)actA, 1, CH_);

    const int DILS[7] = {1, 3, 9, 27, 81, 243, 1};
    _Float16* cur = (_Float16*)actA;
    _Float16* nxt = (_Float16*)actB;
    for (int i = 0; i < 7; ++i) {
        const float* gi = (i == 0) ? bn0_g : bn_g + (i-1)*CH_;
        const float* bi = (i == 0) ? bn0_b : bn_b + (i-1)*CH_;
        k_cv<3,true,true,true,false,true><<<dim3(T_/128,1,B_), 256, 0, stream>>>(
            cur, Wd + (size_t)i*3*CH_*CH_, dil_b + i*CH_, Wp + (size_t)i*CH_*CH_,
            pw_b + i*CH_, stats + i*256, gi, bi, stats + (i+1)*256, nxt, DILS[i], CH_);
        _Float16* sw = cur; cur = nxt; nxt = sw;
    }
    // cur == actB; actA free -> part/At aliases valid from here
    k_tr_at<<<dim3(ATOM_/32, EC_/32), dim3(32,8), 0, stream>>>(sdict, At);

    for (int b = 0; b < B_; ++b) {
        k_cv<1,true,false,false,true,false><<<dim3(T_/128,EC_/128,1), 256, 0, stream>>>(
            cur + (size_t)b*T_*CH_, Wup, up_b, nullptr, nullptr,
            stats + 7*256, bn_g + 6*CH_, bn_b + 6*CH_, nullptr, enc, 1, EC_);
        for (int cc = 0; cc < 4; ++cc) {
            k_gemm<<<dim3(T_/128, 4), 256, 0, stream>>>(At + (size_t)cc*512*EC_, enc, G);
            k_diag<<<dim3(T_/256, 4), 256, 0, stream>>>(G, part + (size_t)cc*4*T_, cc*512);
        }
        k_diag2<<<T_/256, 256, 0, stream>>>(part, out + (size_t)b*T_);
    }
}

// Round 5
// 955.448 us; speedup vs baseline: 4.8815x; 1.0966x over previous
//
#include <hip/hip_runtime.h>
#include <hip/hip_bf16.h>

#define B_ 2
#define T_ 32768
#define CH_ 128
#define EC_ 512
#define ATOM_ 2048
#define FBK_ 512

typedef __attribute__((ext_vector_type(8))) short s16x8;
typedef __attribute__((ext_vector_type(8))) _Float16 f16x8;
typedef __attribute__((ext_vector_type(4))) float f32x4;

__device__ __forceinline__ f16x8 ldh8(const _Float16* p) {
    union { s16x8 s; f16x8 h; } u; u.s = *(const s16x8*)p; return u.h;
}

// ---------------- MFMA filter bank: x[b,1,T] -> spec16[b][t][band] f16 ----------------
__global__ void __launch_bounds__(256) k_fbm(const float* __restrict__ x,
        const _Float16* __restrict__ Wfb, _Float16* __restrict__ spec16) {
    __shared__ _Float16 XA[128][72];
    __shared__ float xw[640];
    int tid = threadIdx.x;
    int lane = tid & 63;
    int wv = tid >> 6, wm = wv >> 1, wn = wv & 1;
    int ln15 = lane & 15, kh = lane >> 4;
    int t0 = blockIdx.x * 128;
    int b = blockIdx.y;

    for (int i = tid; i < 640; i += 256) {
        int g = t0 - 256 + i;
        xw[i] = (g >= 0 && g < T_) ? x[(size_t)b*T_ + g] : 0.f;
    }

    f32x4 acc[4][4];
    f32x4 zero = {0.f,0.f,0.f,0.f};
#pragma unroll
    for (int m = 0; m < 4; ++m)
#pragma unroll
        for (int n = 0; n < 4; ++n) acc[m][n] = zero;

    for (int c = 0; c < 8; ++c) {
        int k0 = c*64;
        __syncthreads();               // xw ready on c==0; XA WAR on c>0
#pragma unroll
        for (int q = 0; q < 4; ++q) {
            int idx = tid + q*256;
            int r = idx >> 3, ko = idx & 7;
            int base = r + k0 + ko*8;
            f16x8 v;
#pragma unroll
            for (int j = 0; j < 8; ++j) v[j] = (_Float16)xw[base + j];
            union { f16x8 h; s16x8 s; } u; u.h = v;
            *(s16x8*)&XA[r][ko*8] = u.s;
        }
        __syncthreads();
#pragma unroll
        for (int kt = 0; kt < 2; ++kt) {
            f16x8 af[4], bf[4];
#pragma unroll
            for (int m = 0; m < 4; ++m) af[m] = ldh8(&XA[wm*64+m*16+ln15][kt*32+kh*8]);
#pragma unroll
            for (int n = 0; n < 4; ++n)
                bf[n] = ldh8(Wfb + (size_t)(wn*64+n*16+ln15)*FBK_ + k0 + kt*32 + kh*8);
#pragma unroll
            for (int m = 0; m < 4; ++m)
#pragma unroll
                for (int n = 0; n < 4; ++n)
                    acc[m][n] = __builtin_amdgcn_mfma_f32_16x16x32_f16(af[m], bf[n], acc[m][n], 0,0,0);
        }
    }
#pragma unroll
    for (int mf = 0; mf < 4; ++mf)
#pragma unroll
        for (int nf = 0; nf < 4; ++nf) {
            int band = wn*64 + nf*16 + ln15;
#pragma unroll
            for (int j = 0; j < 4; ++j) {
                int tl = wm*64 + mf*16 + kh*4 + j;
                spec16[((size_t)b*T_ + t0 + tl)*CH_ + band] = (_Float16)acc[mf][nf][j];
            }
        }
}

// ---------------- weight prep ----------------
__global__ void k_pw7(const float* __restrict__ w, _Float16* __restrict__ W7) {
    int i = blockIdx.x*256+threadIdx.x;
    if (i >= 7*16384) return;
    int k = i / 16384, r = i % 16384; int co = r >> 7, ci = r & 127;
    W7[i] = (_Float16)w[(co*CH_+ci)*7 + k];
}
__global__ void k_pwd(const float* __restrict__ w, _Float16* __restrict__ Wd) {
    int i = blockIdx.x*256+threadIdx.x;
    if (i >= 7*3*16384) return;
    int st = i / 49152, r = i % 49152; int k = r / 16384, r2 = r % 16384;
    int co = r2 >> 7, ci = r2 & 127;
    Wd[i] = (_Float16)w[((size_t)(st*CH_+co)*CH_+ci)*3 + k];
}
__global__ void k_cast(const float* __restrict__ in, _Float16* __restrict__ out, int n) {
    int i = blockIdx.x*256+threadIdx.x;
    if (i < n) out[i] = (_Float16)in[i];
}
__global__ void k_zero(float* __restrict__ p, int n) {
    int i = blockIdx.x*256+threadIdx.x;
    if (i < n) p[i] = 0.f;
}

// ---------------- fused MFMA conv block (weights direct from global/L2) ----------------
template<int NTAP, bool NORM, bool PW, bool LRELU, bool RELU, bool STATS>
__global__ void __launch_bounds__(256) k_cv(
        const _Float16* __restrict__ in, const _Float16* __restrict__ W,
        const float* __restrict__ bias, const _Float16* __restrict__ Wp_,
        const float* __restrict__ pbias, const float* __restrict__ stats_in,
        const float* __restrict__ g, const float* __restrict__ bb,
        float* __restrict__ stats_out, _Float16* __restrict__ outp,
        int dil, int ostride) {
    __shared__ _Float16 XT[128][136];
    __shared__ _Float16 Y1[PW?128:1][PW?136:1];
    __shared__ float AffA[NORM?128:1], AffB[NORM?128:1];

    int tid = threadIdx.x;
    int lane = tid & 63;
    int wv = tid >> 6, wm = wv >> 1, wn = wv & 1;
    int ln15 = lane & 15, kh = lane >> 4;
    int t0 = blockIdx.x * 128;
    int nch = blockIdx.y;
    int b = blockIdx.z;
    int ncol0 = nch * 128;
    const _Float16* inb = in + (size_t)b*T_*CH_;
    const _Float16* W_eff = W + (size_t)ncol0*CH_;
    const float* bias_eff = bias + ncol0;

    if (NORM) {
        if (tid < 128) {
            const float invN = 1.f/(float)(B_*T_);
            float s1 = stats_in[tid], s2 = stats_in[128+tid];
            float m = s1*invN, var = s2*invN - m*m;
            float A = rsqrtf(var + 1e-5f) * g[tid];
            AffA[tid] = A; AffB[tid] = bb[tid] - m*A;
        }
    }

    f32x4 acc[4][4];
    f32x4 zero = {0.f,0.f,0.f,0.f};
#pragma unroll
    for (int m = 0; m < 4; ++m)
#pragma unroll
        for (int n = 0; n < 4; ++n) acc[m][n] = zero;

    for (int tap = 0; tap < NTAP; ++tap) {
        int tp = tap;
        if (PW) tp = (tap==0) ? 0 : ((tap==1) ? 2 : 1);   // center tap LAST (kept for residual)
        int off = (tp - NTAP/2)*dil;
        const _Float16* Wt = W_eff + (size_t)tp*CH_*CH_;
        __syncthreads();               // AffA ready (tap0) / XT WAR (tap>0)
#pragma unroll
        for (int q = 0; q < 8; ++q) {
            int idx = tid + q*256;
            int lt = idx >> 4, ck = idx & 15;
            int gt = t0 + lt + off;
            s16x8 v = {0,0,0,0,0,0,0,0};
            bool valid = (gt >= 0 && gt < T_);
            if (valid) {
                v = *(const s16x8*)(inb + (size_t)gt*CH_ + ck*8);
                if (NORM) {
                    union {s16x8 s; f16x8 h;} u; u.s = v;
                    f16x8 r;
#pragma unroll
                    for (int j = 0; j < 8; ++j) {
                        float f = (float)u.h[j];
                        f = fmaf(f, AffA[ck*8+j], AffB[ck*8+j]);
                        r[j] = (_Float16)f;
                    }
                    union {f16x8 h; s16x8 s;} w2; w2.h = r; v = w2.s;
                }
            }
            *(s16x8*)&XT[lt][ck*8] = v;
        }
        __syncthreads();
#pragma unroll
        for (int kt = 0; kt < 4; ++kt) {
            f16x8 af[4], bf[4];
#pragma unroll
            for (int m = 0; m < 4; ++m) af[m] = ldh8(&XT[wm*64+m*16+ln15][kt*32+kh*8]);
#pragma unroll
            for (int n = 0; n < 4; ++n)
                bf[n] = ldh8(Wt + (size_t)(wn*64+n*16+ln15)*CH_ + kt*32 + kh*8);
#pragma unroll
            for (int m = 0; m < 4; ++m)
#pragma unroll
                for (int n = 0; n < 4; ++n)
                    acc[m][n] = __builtin_amdgcn_mfma_f32_16x16x32_f16(af[m], bf[n], acc[m][n], 0,0,0);
        }
    }

    if (PW) {
#pragma unroll
        for (int mf = 0; mf < 4; ++mf)
#pragma unroll
            for (int nf = 0; nf < 4; ++nf) {
                int co = wn*64 + nf*16 + ln15;
                float bv = bias_eff[co];
#pragma unroll
                for (int j = 0; j < 4; ++j) {
                    int tl = wm*64 + mf*16 + kh*4 + j;
                    Y1[tl][co] = (_Float16)(acc[mf][nf][j] + bv);
                }
            }
#pragma unroll
        for (int m = 0; m < 4; ++m)
#pragma unroll
            for (int n = 0; n < 4; ++n) acc[m][n] = zero;
        __syncthreads();
#pragma unroll
        for (int kt = 0; kt < 4; ++kt) {
            f16x8 af[4], bf[4];
#pragma unroll
            for (int m = 0; m < 4; ++m) af[m] = ldh8(&Y1[wm*64+m*16+ln15][kt*32+kh*8]);
#pragma unroll
            for (int n = 0; n < 4; ++n)
                bf[n] = ldh8(Wp_ + (size_t)(wn*64+n*16+ln15)*CH_ + kt*32 + kh*8);
#pragma unroll
            for (int m = 0; m < 4; ++m)
#pragma unroll
                for (int n = 0; n < 4; ++n)
                    acc[m][n] = __builtin_amdgcn_mfma_f32_16x16x32_f16(af[m], bf[n], acc[m][n], 0,0,0);
        }
    }

#pragma unroll
    for (int nf = 0; nf < 4; ++nf) {
        int co = wn*64 + nf*16 + ln15;
        float bfin = PW ? pbias[co] : bias_eff[co];
        float s = 0.f, s2 = 0.f;
#pragma unroll
        for (int mf = 0; mf < 4; ++mf) {
#pragma unroll
            for (int j = 0; j < 4; ++j) {
                int tl = wm*64 + mf*16 + kh*4 + j;
                float v = acc[mf][nf][j] + bfin;
                if (PW) v += (float)XT[tl][co];    // residual = normalized center tile
                if (LRELU) v = v >= 0.f ? v : 0.2f*v;
                if (RELU)  v = fmaxf(v, 0.f);
                outp[((size_t)b*T_ + t0 + tl)*ostride + ncol0 + co] = (_Float16)v;
                if (STATS) { s += v; s2 += v*v; }
            }
        }
        if (STATS) {
            s  += __shfl_down(s, 16);  s  += __shfl_down(s, 32);
            s2 += __shfl_down(s2, 16); s2 += __shfl_down(s2, 32);
            if (kh == 0) {
                atomicAdd(&stats_out[co], s);
                atomicAdd(&stats_out[128+co], s2);
            }
        }
    }
}

// ---------------- transpose static_dict [512][2048] fp32 -> At [2048][512] f16 ----------------
__global__ void k_tr_at(const float* __restrict__ sd, _Float16* __restrict__ At) {
    __shared__ float tile[32][33];
    int tau0 = blockIdx.x*32;
    int c0 = blockIdx.y*32;
    int tx = threadIdx.x, ty = threadIdx.y;
#pragma unroll
    for (int j = 0; j < 4; ++j)
        tile[ty+j*8][tx] = sd[(size_t)(c0+ty+j*8)*ATOM_ + tau0 + tx];
    __syncthreads();
#pragma unroll
    for (int j = 0; j < 4; ++j)
        At[(size_t)(tau0+ty+j*8)*EC_ + c0 + tx] = (_Float16)tile[tx][ty+j*8];
}

// ---------------- GEMM + fused anti-diagonal reduction ----------------
// out[b][tau+s] += sum over tile of At[tau][c]*enc[b][s][c]
__global__ void __launch_bounds__(256) k_gemm(const _Float16* __restrict__ At,
                                              const _Float16* __restrict__ enc,
                                              float* __restrict__ out) {
    __shared__ _Float16 lA[128][72];
    __shared__ _Float16 lB[128][72];
    __shared__ float pt[256];
    int tid = threadIdx.x;
    int lane = tid & 63;
    int wv = tid >> 6;
    int wm = wv >> 1, wn = wv & 1;
    int sT = blockIdx.x;
    int tT = blockIdx.y;
    int b  = blockIdx.z;
    const _Float16* Et = enc + (size_t)b*T_*EC_;
    int ln15 = lane & 15, kh = lane >> 4;
    f32x4 acc[4][4];
    f32x4 zero = {0.f,0.f,0.f,0.f};
#pragma unroll
    for (int m = 0; m < 4; ++m)
#pragma unroll
        for (int n = 0; n < 4; ++n) acc[m][n] = zero;

    for (int kt = 0; kt < 8; ++kt) {
#pragma unroll
        for (int r = 0; r < 4; ++r) {
            int idx = tid + r*256;
            int row = idx >> 3, ch = idx & 7;
            *(s16x8*)&lA[row][ch*8] = *(const s16x8*)(At + ((size_t)(tT*128+row))*EC_ + kt*64 + ch*8);
            *(s16x8*)&lB[row][ch*8] = *(const s16x8*)(Et + ((size_t)(sT*128+row))*EC_ + kt*64 + ch*8);
        }
        __syncthreads();
#pragma unroll
        for (int kk = 0; kk < 2; ++kk) {
            f16x8 af[4], bfr[4];
#pragma unroll
            for (int m = 0; m < 4; ++m)
                af[m] = ldh8(&lA[wm*64 + m*16 + ln15][kk*32 + kh*8]);
#pragma unroll
            for (int n = 0; n < 4; ++n)
                bfr[n] = ldh8(&lB[wn*64 + n*16 + ln15][kk*32 + kh*8]);
#pragma unroll
            for (int m = 0; m < 4; ++m)
#pragma unroll
                for (int n = 0; n < 4; ++n)
                    acc[m][n] = __builtin_amdgcn_mfma_f32_16x16x32_f16(af[m], bfr[n], acc[m][n], 0, 0, 0);
        }
        __syncthreads();
    }

    // anti-diagonal reduce: row = tau_local (m-dim), col = s_local (n-dim); t_local = row+col
    pt[tid] = 0.f;
    __syncthreads();
#pragma unroll
    for (int mn = 0; mn <= 6; ++mn) {
#pragma unroll
        for (int j = 0; j < 4; ++j) {
            float v = 0.f;
#pragma unroll
            for (int m = 0; m < 4; ++m) {
                int n = mn - m;
                if (n >= 0 && n < 4) v += acc[m][n][j];
            }
            int tl = (wm + wn)*64 + mn*16 + kh*4 + j + ln15;
            unsafeAtomicAdd(&pt[tl], v);
        }
    }
    __syncthreads();
    if (tid < 255) {
        int tg = tT*128 + sT*128 + tid;
        if (tg < T_) unsafeAtomicAdd(&out[(size_t)b*T_ + tg], pt[tid]);
    }
}

__global__ void k_fill(float* __restrict__ out, float val) {
    out[blockIdx.x*256 + threadIdx.x] = val;
}

extern "C" void kernel_launch(void* const* d_in, const int* in_sizes, int n_in,
                              void* d_out, int out_size, void* d_ws, size_t ws_size,
                              hipStream_t stream) {
    const float* x       = (const float*)d_in[0];
    const float* fb_w    = (const float*)d_in[1];
    const float* conv0_w = (const float*)d_in[2];
    const float* conv0_b = (const float*)d_in[3];
    const float* bn0_g   = (const float*)d_in[4];
    const float* bn0_b   = (const float*)d_in[5];
    const float* dil_w   = (const float*)d_in[6];
    const float* dil_b   = (const float*)d_in[7];
    const float* pw_w    = (const float*)d_in[8];
    const float* pw_b    = (const float*)d_in[9];
    const float* bn_g    = (const float*)d_in[10];
    const float* bn_b    = (const float*)d_in[11];
    const float* up_w    = (const float*)d_in[12];
    const float* up_b    = (const float*)d_in[13];
    const float* sdict   = (const float*)d_in[14];
    float* out = (float*)d_out;
    char* ws = (char*)d_ws;

    // layout (bytes)
    const size_t R1   = 33554432;   // spec16 -> enc[0]
    const size_t R2   = 33554432;   // enc[1]  (enc = r1, 67MB contiguous)
    const size_t ACT  = 16777216;   // f16 [b][t][c]
    char* r1   = ws;
    char* actA = ws + R1 + R2;
    char* actB = actA + ACT;
    char* wreg = actB + ACT;
    _Float16* W7   = (_Float16*)wreg;                      // 7*16384
    _Float16* Wd   = W7 + 7*16384;                         // 7*3*16384
    _Float16* Wp   = Wd + 7*3*16384;                       // 7*16384
    _Float16* Wup  = Wp + 7*16384;                         // 65536
    _Float16* Wfb  = Wup + 65536;                          // 65536
    float* stats   = (float*)(Wfb + 65536);                // 8*2*128 floats
    const size_t TOTAL = R1 + R2 + 2*ACT
                       + (7*16384 + 7*3*16384 + 7*16384 + 65536 + 65536)*2 + 8*2*128*4;
    if (ws_size < TOTAL) {
        k_fill<<<(out_size+255)/256, 256, 0, stream>>>(out, 12345.0f);
        return;
    }
    _Float16* spec16 = (_Float16*)r1;
    _Float16* enc = (_Float16*)r1;            // [b][t][c], 67MB (spec16 dead after conv0)
    _Float16* At  = (_Float16*)(actA + 2097152);  // alias in actA (free after conv stack)

    // prep
    k_zero<<<(2048+255)/256, 256, 0, stream>>>(stats, 8*2*128);
    k_pw7<<<(7*16384+255)/256, 256, 0, stream>>>(conv0_w, W7);
    k_pwd<<<(7*3*16384+255)/256, 256, 0, stream>>>(dil_w, Wd);
    k_cast<<<(7*16384+255)/256, 256, 0, stream>>>(pw_w, Wp, 7*16384);
    k_cast<<<(65536+255)/256, 256, 0, stream>>>(up_w, Wup, 65536);
    k_cast<<<(65536+255)/256, 256, 0, stream>>>(fb_w, Wfb, 65536);

    // front: MFMA filter bank, direct time-major f16
    k_fbm<<<dim3(T_/128, B_), 256, 0, stream>>>(x, Wfb, spec16);
    k_cv<7,false,false,true,false,true><<<dim3(T_/128,1,B_), 256, 0, stream>>>(
        spec16, W7, conv0_b, nullptr, nullptr, nullptr, nullptr, nullptr,
        stats + 0, (_Float16*)actA, 1, CH_);

    const int DILS[7] = {1, 3, 9, 27, 81, 243, 1};
    _Float16* cur = (_Float16*)actA;
    _Float16* nxt = (_Float16*)actB;
    for (int i = 0; i < 7; ++i) {
        const float* gi = (i == 0) ? bn0_g : bn_g + (i-1)*CH_;
        const float* bi = (i == 0) ? bn0_b : bn_b + (i-1)*CH_;
        k_cv<3,true,true,true,false,true><<<dim3(T_/128,1,B_), 256, 0, stream>>>(
            cur, Wd + (size_t)i*3*CH_*CH_, dil_b + i*CH_, Wp + (size_t)i*CH_*CH_,
            pw_b + i*CH_, stats + i*256, gi, bi, stats + (i+1)*256, nxt, DILS[i], CH_);
        _Float16* sw = cur; cur = nxt; nxt = sw;
    }
    // cur == actB; actA free -> At alias valid; r1/r2 free for enc (both batches)

    k_tr_at<<<dim3(ATOM_/32, EC_/32), dim3(32,8), 0, stream>>>(sdict, At);
    // up-projection + relu -> enc[b][t][c] f16 (both batches)
    k_cv<1,true,false,false,true,false><<<dim3(T_/128,EC_/128,B_), 256, 0, stream>>>(
        cur, Wup, up_b, nullptr, nullptr,
        stats + 7*256, bn_g + 6*CH_, bn_b + 6*CH_, nullptr, enc, 1, EC_);

    // dictionary conv: zero out, then GEMM with fused anti-diagonal atomics
    k_zero<<<(B_*T_+255)/256, 256, 0, stream>>>(out, B_*T_);
    k_gemm<<<dim3(T_/128, ATOM_/128, B_), 256, 0, stream>>>(At, enc, out);
}